// Round 1
// baseline (105.145 us; speedup 1.0000x reference)
//
#include <hip/hip_runtime.h>
#include <math.h>

#define BB 16
#define NN 8
#define KK 2048
#define DD 512
#define CC 11
#define BN (BB*NN)          // 128
#define NCHUNK 16
#define KCHUNK (KK/NCHUNK)  // 128
#define EPSN 1e-12f
#define ALPHA 0.9f

struct f8 { float v[8]; };

__device__ __forceinline__ f8 load8(const float* base, int l) {
    const float4* p = (const float4*)base;
    float4 x = p[l];
    float4 y = p[l + 64];
    f8 r;
    r.v[0] = x.x; r.v[1] = x.y; r.v[2] = x.z; r.v[3] = x.w;
    r.v[4] = y.x; r.v[5] = y.y; r.v[6] = y.z; r.v[7] = y.w;
    return r;
}

__device__ __forceinline__ float wave_reduce(float v) {
    #pragma unroll
    for (int off = 1; off < 64; off <<= 1)
        v += __shfl_xor(v, off, 64);
    return v;
}

__device__ __forceinline__ int clamp_cat(int c) {
    c = c - 1;
    return c < 0 ? 0 : (c > 10 ? 10 : c);
}

// Kernel 1: sim_pos per (b,n). 128 blocks x 64 threads.
__global__ __launch_bounds__(64)
void k1_simpos(const float* __restrict__ pred, const float* __restrict__ pos,
               const float* __restrict__ centers, const int* __restrict__ cats,
               float* __restrict__ simpos) {
    int bn = blockIdx.x;
    int b  = bn / NN;
    int l  = threadIdx.x;
    int cat = clamp_cat(cats[bn]);

    f8 pr = load8(pred + ((size_t)b * CC + cat) * DD, l);
    f8 cc = load8(centers + (size_t)cat * DD, l);
    f8 po = load8(pos + (size_t)bn * DD, l);

    float ssa = 0.f, ssb = 0.f;
    float a[8], p[8];
    #pragma unroll
    for (int j = 0; j < 8; ++j) {
        a[j] = pr.v[j] - cc.v[j];
        p[j] = po.v[j] - cc.v[j];
        ssa += a[j] * a[j];
        ssb += p[j] * p[j];
    }
    ssa = wave_reduce(ssa);
    ssb = wave_reduce(ssb);
    float ia = 1.0f / sqrtf(fmaxf(ssa, EPSN));
    float ib = 1.0f / sqrtf(fmaxf(ssb, EPSN));

    float dp = 0.f;
    #pragma unroll
    for (int j = 0; j < 8; ++j)
        dp += (a[j] * ia) * (p[j] * ib);
    dp = wave_reduce(dp);

    if (l == 0) simpos[bn] = dp;
}

// Kernel 2: masked exp-sum over negatives. 128*NCHUNK blocks x 256 threads.
__global__ __launch_bounds__(256)
void k2_neg(const float* __restrict__ pred, const float* __restrict__ neg,
            const float* __restrict__ centers, const int* __restrict__ cats,
            const float* __restrict__ simpos, float* __restrict__ partials) {
    int blk   = blockIdx.x;
    int bn    = blk / NCHUNK;
    int chunk = blk % NCHUNK;
    int b     = bn / NN;
    int wave  = threadIdx.x >> 6;
    int l     = threadIdx.x & 63;

    int cat = clamp_cat(cats[bn]);

    f8 cc = load8(centers + (size_t)cat * DD, l);
    f8 pr = load8(pred + ((size_t)b * CC + cat) * DD, l);

    float pn[8];
    float ss = 0.f;
    #pragma unroll
    for (int j = 0; j < 8; ++j) {
        pn[j] = pr.v[j] - cc.v[j];
        ss += pn[j] * pn[j];
    }
    ss = wave_reduce(ss);
    float inv = 1.0f / sqrtf(fmaxf(ss, EPSN));
    #pragma unroll
    for (int j = 0; j < 8; ++j) pn[j] *= inv;

    float sp = simpos[bn];
    float acc = 0.f;

    const float* nbase = neg + ((size_t)bn * KK + (size_t)chunk * KCHUNK) * DD;

    for (int i = wave; i < KCHUNK; i += 4) {
        f8 nv = load8(nbase + (size_t)i * DD, l);
        float ds = 0.f, s2 = 0.f;
        #pragma unroll
        for (int j = 0; j < 8; ++j) {
            float d = nv.v[j] - cc.v[j];
            ds += pn[j] * d;
            s2 += d * d;
        }
        #pragma unroll
        for (int off = 1; off < 64; off <<= 1) {
            ds += __shfl_xor(ds, off, 64);
            s2 += __shfl_xor(s2, off, 64);
        }
        float sn = ds * (1.0f / sqrtf(fmaxf(s2, EPSN)));
        if (sn - sp >= ALPHA * sp) acc += expf(sn);
    }

    __shared__ float sacc[4];
    if (l == 0) sacc[wave] = acc;
    __syncthreads();
    if (threadIdx.x == 0)
        partials[blk] = sacc[0] + sacc[1] + sacc[2] + sacc[3];
}

// Kernel 3: final loss mean. 1 block x 128 threads.
__global__ __launch_bounds__(128)
void k3_final(const float* __restrict__ simpos, const float* __restrict__ partials,
              float* __restrict__ out) {
    int bn = threadIdx.x;
    float ns = 0.f;
    for (int i = 0; i < NCHUNK; ++i)
        ns += partials[bn * NCHUNK + i];
    float sp = simpos[bn];
    float ep = expf(sp);
    float denom = fmaxf(ep + ns, 1e-7f);
    float loss = -logf(ep / denom);

    __shared__ float s[BN];
    s[bn] = loss;
    __syncthreads();
    #pragma unroll
    for (int st = 64; st > 0; st >>= 1) {
        if (bn < st) s[bn] += s[bn + st];
        __syncthreads();
    }
    if (bn == 0) out[0] = s[0] / (float)BN;
}

extern "C" void kernel_launch(void* const* d_in, const int* in_sizes, int n_in,
                              void* d_out, int out_size, void* d_ws, size_t ws_size,
                              hipStream_t stream) {
    const float* pred    = (const float*)d_in[0];  // (B, C, D)
    const float* pos     = (const float*)d_in[1];  // (B, N, D)
    const float* neg     = (const float*)d_in[2];  // (B, N, K, D)
    const float* centers = (const float*)d_in[3];  // (C, D)
    const int*   cats    = (const int*)d_in[4];    // (B, N)

    float* out = (float*)d_out;

    float* simpos   = (float*)d_ws;            // 128 floats
    float* partials = simpos + BN;             // 128*16 floats

    k1_simpos<<<BN, 64, 0, stream>>>(pred, pos, centers, cats, simpos);
    k2_neg<<<BN * NCHUNK, 256, 0, stream>>>(pred, neg, centers, cats, simpos, partials);
    k3_final<<<1, 128, 0, stream>>>(simpos, partials, out);
}

// Round 2
// 101.693 us; speedup vs baseline: 1.0339x; 1.0339x over previous
//
#include <hip/hip_runtime.h>
#include <math.h>

#define BB 16
#define NN 8
#define KK 2048
#define DD 512
#define CC 11
#define BN (BB*NN)          // 128
#define NCHUNK 16
#define KCHUNK (KK/NCHUNK)  // 128 vectors per block
#define EPSN 1e-12f
#define ALPHA 0.9f

struct f8 { float v[8]; };

__device__ __forceinline__ f8 load8(const float* base, int l) {
    const float4* p = (const float4*)base;
    float4 x = p[l];
    float4 y = p[l + 64];
    f8 r;
    r.v[0] = x.x; r.v[1] = x.y; r.v[2] = x.z; r.v[3] = x.w;
    r.v[4] = y.x; r.v[5] = y.y; r.v[6] = y.z; r.v[7] = y.w;
    return r;
}

__device__ __forceinline__ float wave_reduce64(float v) {
    #pragma unroll
    for (int off = 1; off < 64; off <<= 1)
        v += __shfl_xor(v, off, 64);
    return v;
}

__device__ __forceinline__ int clamp_cat(int c) {
    c = c - 1;
    return c < 0 ? 0 : (c > 10 ? 10 : c);
}

// Kernel 1: sim_pos per (b,n). 128 blocks x 64 threads.
__global__ __launch_bounds__(64)
void k1_simpos(const float* __restrict__ pred, const float* __restrict__ pos,
               const float* __restrict__ centers, const int* __restrict__ cats,
               float* __restrict__ simpos) {
    int bn = blockIdx.x;
    int b  = bn / NN;
    int l  = threadIdx.x;
    int cat = clamp_cat(cats[bn]);

    f8 pr = load8(pred + ((size_t)b * CC + cat) * DD, l);
    f8 cc = load8(centers + (size_t)cat * DD, l);
    f8 po = load8(pos + (size_t)bn * DD, l);

    float ssa = 0.f, ssb = 0.f;
    float a[8], p[8];
    #pragma unroll
    for (int j = 0; j < 8; ++j) {
        a[j] = pr.v[j] - cc.v[j];
        p[j] = po.v[j] - cc.v[j];
        ssa += a[j] * a[j];
        ssb += p[j] * p[j];
    }
    ssa = wave_reduce64(ssa);
    ssb = wave_reduce64(ssb);
    float ia = 1.0f / sqrtf(fmaxf(ssa, EPSN));
    float ib = 1.0f / sqrtf(fmaxf(ssb, EPSN));

    float dp = 0.f;
    #pragma unroll
    for (int j = 0; j < 8; ++j)
        dp += (a[j] * ia) * (p[j] * ib);
    dp = wave_reduce64(dp);

    if (l == 0) simpos[bn] = dp;
}

// Kernel 2: masked exp-sum over negatives. 128*NCHUNK blocks x 256 threads.
// Each wave processes 2 k-vectors per iteration via 32-lane groups:
//   group g = lane>>5 owns vector 2*pair+g; lane sub = lane&31 holds 16
//   elements (float4 indices sub + j*32). Reduction = 5 xor stages over the
//   32-lane group (shared by both vectors). Explicit prefetch of the next
//   pair keeps 4 loads in flight across the shuffle chain.
__global__ __launch_bounds__(256)
void k2_neg(const float* __restrict__ pred, const float* __restrict__ neg,
            const float* __restrict__ centers, const int* __restrict__ cats,
            const float* __restrict__ simpos, float* __restrict__ partials) {
    int blk   = blockIdx.x;
    int bn    = blk / NCHUNK;
    int chunk = blk % NCHUNK;
    int b     = bn / NN;
    int wave  = threadIdx.x >> 6;
    int l     = threadIdx.x & 63;
    int g     = l >> 5;       // vector-of-pair select
    int sub   = l & 31;       // lane within 32-group

    int cat = clamp_cat(cats[bn]);

    const float4* c4 = (const float4*)(centers + (size_t)cat * DD);
    const float4* p4 = (const float4*)(pred + ((size_t)b * CC + cat) * DD);

    // per-lane slice of center and normalized pred (16 floats each)
    float cc[16], pn[16];
    float ss = 0.f;
    #pragma unroll
    for (int j = 0; j < 4; ++j) {
        float4 cv = c4[sub + j * 32];
        float4 pv = p4[sub + j * 32];
        cc[j*4+0] = cv.x; cc[j*4+1] = cv.y; cc[j*4+2] = cv.z; cc[j*4+3] = cv.w;
        float d0 = pv.x - cv.x, d1 = pv.y - cv.y, d2 = pv.z - cv.z, d3 = pv.w - cv.w;
        pn[j*4+0] = d0; pn[j*4+1] = d1; pn[j*4+2] = d2; pn[j*4+3] = d3;
        ss += d0*d0 + d1*d1 + d2*d2 + d3*d3;
    }
    #pragma unroll
    for (int off = 1; off < 32; off <<= 1) ss += __shfl_xor(ss, off, 64);
    float inv = 1.0f / sqrtf(fmaxf(ss, EPSN));
    #pragma unroll
    for (int j = 0; j < 16; ++j) pn[j] *= inv;

    float sp = simpos[bn];
    float acc = 0.f;

    const float4* nb4 = (const float4*)(neg + ((size_t)bn * KK + (size_t)chunk * KCHUNK) * DD);
    // pair index p = wave + 4*it (it = 0..15); this wave's vector = 2*p + g
    const int V4 = DD / 4;  // 128 float4 per vector

    float4 cur[4];
    {
        const float4* vb = nb4 + (size_t)(2 * wave + g) * V4;
        #pragma unroll
        for (int j = 0; j < 4; ++j) cur[j] = vb[sub + j * 32];
    }

    for (int it = 0; it < 16; ++it) {
        float4 nxt[4] = {cur[0], cur[1], cur[2], cur[3]};
        if (it + 1 < 16) {
            const float4* vb = nb4 + (size_t)(2 * (wave + 4 * (it + 1)) + g) * V4;
            #pragma unroll
            for (int j = 0; j < 4; ++j) nxt[j] = vb[sub + j * 32];
        }

        float ds = 0.f, s2 = 0.f;
        #pragma unroll
        for (int j = 0; j < 4; ++j) {
            float d;
            d = cur[j].x - cc[j*4+0]; ds += pn[j*4+0] * d; s2 += d * d;
            d = cur[j].y - cc[j*4+1]; ds += pn[j*4+1] * d; s2 += d * d;
            d = cur[j].z - cc[j*4+2]; ds += pn[j*4+2] * d; s2 += d * d;
            d = cur[j].w - cc[j*4+3]; ds += pn[j*4+3] * d; s2 += d * d;
        }
        #pragma unroll
        for (int off = 1; off < 32; off <<= 1) {
            ds += __shfl_xor(ds, off, 64);
            s2 += __shfl_xor(s2, off, 64);
        }
        float sn = ds * (1.0f / sqrtf(fmaxf(s2, EPSN)));
        if (sub == 0 && (sn - sp >= ALPHA * sp)) acc += expf(sn);

        #pragma unroll
        for (int j = 0; j < 4; ++j) cur[j] = nxt[j];
    }

    // lanes 0 and 32 hold the two group partials
    acc += __shfl_xor(acc, 32, 64);

    __shared__ float sacc[4];
    if (l == 0) sacc[wave] = acc;
    __syncthreads();
    if (threadIdx.x == 0)
        partials[blk] = sacc[0] + sacc[1] + sacc[2] + sacc[3];
}

// Kernel 3: final loss mean. 1 block x 128 threads.
__global__ __launch_bounds__(128)
void k3_final(const float* __restrict__ simpos, const float* __restrict__ partials,
              float* __restrict__ out) {
    int bn = threadIdx.x;
    float ns = 0.f;
    for (int i = 0; i < NCHUNK; ++i)
        ns += partials[bn * NCHUNK + i];
    float sp = simpos[bn];
    float ep = expf(sp);
    float denom = fmaxf(ep + ns, 1e-7f);
    float loss = -logf(ep / denom);

    __shared__ float s[BN];
    s[bn] = loss;
    __syncthreads();
    #pragma unroll
    for (int st = 64; st > 0; st >>= 1) {
        if (bn < st) s[bn] += s[bn + st];
        __syncthreads();
    }
    if (bn == 0) out[0] = s[0] / (float)BN;
}

extern "C" void kernel_launch(void* const* d_in, const int* in_sizes, int n_in,
                              void* d_out, int out_size, void* d_ws, size_t ws_size,
                              hipStream_t stream) {
    const float* pred    = (const float*)d_in[0];  // (B, C, D)
    const float* pos     = (const float*)d_in[1];  // (B, N, D)
    const float* neg     = (const float*)d_in[2];  // (B, N, K, D)
    const float* centers = (const float*)d_in[3];  // (C, D)
    const int*   cats    = (const int*)d_in[4];    // (B, N)

    float* out = (float*)d_out;

    float* simpos   = (float*)d_ws;            // 128 floats
    float* partials = simpos + BN;             // 128*16 floats

    k1_simpos<<<BN, 64, 0, stream>>>(pred, pos, centers, cats, simpos);
    k2_neg<<<BN * NCHUNK, 256, 0, stream>>>(pred, neg, centers, cats, simpos, partials);
    k3_final<<<1, 128, 0, stream>>>(simpos, partials, out);
}

// Round 4
// 91.382 us; speedup vs baseline: 1.1506x; 1.1128x over previous
//
#include <hip/hip_runtime.h>
#include <math.h>

#define BB 16
#define NN 8
#define KK 2048
#define DD 512
#define CC 11
#define BN (BB*NN)          // 128
#define NCHUNK 16
#define KCHUNK (KK/NCHUNK)  // 128 vectors per block
#define EPSN 1e-12f
#define ALPHA 0.9f

typedef float fx4 __attribute__((ext_vector_type(4)));

__device__ __forceinline__ int clamp_cat(int c) {
    c = c - 1;
    return c < 0 ? 0 : (c > 10 ? 10 : c);
}

// Kernel 2 (fused sim_pos): masked exp-sum over negatives.
// 128*NCHUNK blocks x 256 threads. Each wave processes 2 k-vectors per
// iteration via 32-lane groups; reduction = 5 xor stages shared by both
// vectors; depth-1 prefetch keeps 4 dwordx4 loads in flight across the
// compute+shuffle chain. Gallery loads are nontemporal (zero reuse).
__global__ __launch_bounds__(256)
void k2_neg(const float* __restrict__ pred, const float* __restrict__ pos,
            const float* __restrict__ neg, const float* __restrict__ centers,
            const int* __restrict__ cats,
            float* __restrict__ simpos, float* __restrict__ partials) {
    int blk   = blockIdx.x;
    int bn    = blk / NCHUNK;
    int chunk = blk % NCHUNK;
    int b     = bn / NN;
    int wave  = threadIdx.x >> 6;
    int l     = threadIdx.x & 63;
    int g     = l >> 5;       // vector-of-pair select
    int sub   = l & 31;       // lane within 32-group

    int cat = clamp_cat(cats[bn]);

    const float4* c4 = (const float4*)(centers + (size_t)cat * DD);
    const float4* p4 = (const float4*)(pred + ((size_t)b * CC + cat) * DD);
    const float4* q4 = (const float4*)(pos + (size_t)bn * DD);

    // per-lane slice (16 floats) of center and pred-center; fused sim_pos
    float cc[16], pn[16];
    float ssa = 0.f, ssp = 0.f, dap = 0.f;
    #pragma unroll
    for (int j = 0; j < 4; ++j) {
        float4 cv = c4[sub + j * 32];
        float4 pv = p4[sub + j * 32];
        float4 qv = q4[sub + j * 32];
        cc[j*4+0] = cv.x; cc[j*4+1] = cv.y; cc[j*4+2] = cv.z; cc[j*4+3] = cv.w;
        float a0 = pv.x - cv.x, a1 = pv.y - cv.y, a2 = pv.z - cv.z, a3 = pv.w - cv.w;
        float q0 = qv.x - cv.x, q1 = qv.y - cv.y, q2 = qv.z - cv.z, q3 = qv.w - cv.w;
        pn[j*4+0] = a0; pn[j*4+1] = a1; pn[j*4+2] = a2; pn[j*4+3] = a3;
        ssa += a0*a0 + a1*a1 + a2*a2 + a3*a3;
        ssp += q0*q0 + q1*q1 + q2*q2 + q3*q3;
        dap += a0*q0 + a1*q1 + a2*q2 + a3*q3;
    }
    #pragma unroll
    for (int off = 1; off < 32; off <<= 1) {
        ssa += __shfl_xor(ssa, off, 64);
        ssp += __shfl_xor(ssp, off, 64);
        dap += __shfl_xor(dap, off, 64);
    }
    float ia = 1.0f / sqrtf(fmaxf(ssa, EPSN));
    float ib = 1.0f / sqrtf(fmaxf(ssp, EPSN));
    float sp = dap * ia * ib;
    #pragma unroll
    for (int j = 0; j < 16; ++j) pn[j] *= ia;

    if (chunk == 0 && threadIdx.x == 0) simpos[bn] = sp;

    float acc = 0.f;

    const fx4* nb4 = (const fx4*)(neg + ((size_t)bn * KK + (size_t)chunk * KCHUNK) * DD);
    const int V4 = DD / 4;  // 128 float4 per vector

    fx4 cur[4];
    {
        const fx4* vb = nb4 + (size_t)(2 * wave + g) * V4;
        #pragma unroll
        for (int j = 0; j < 4; ++j) cur[j] = __builtin_nontemporal_load(&vb[sub + j * 32]);
    }

    auto process = [&](const fx4* v) {
        float ds = 0.f, s2 = 0.f;
        #pragma unroll
        for (int j = 0; j < 4; ++j) {
            #pragma unroll
            for (int e = 0; e < 4; ++e) {
                float d = v[j][e] - cc[j*4+e];
                ds += pn[j*4+e] * d;
                s2 += d * d;
            }
        }
        #pragma unroll
        for (int off = 1; off < 32; off <<= 1) {
            ds += __shfl_xor(ds, off, 64);
            s2 += __shfl_xor(s2, off, 64);
        }
        float sn = ds * (1.0f / sqrtf(fmaxf(s2, EPSN)));
        if (sub == 0 && (sn - sp >= ALPHA * sp)) acc += expf(sn);
    };

    for (int it = 0; it < 15; ++it) {
        fx4 nxt[4];
        const fx4* vb = nb4 + (size_t)(2 * (wave + 4 * (it + 1)) + g) * V4;
        #pragma unroll
        for (int j = 0; j < 4; ++j) nxt[j] = __builtin_nontemporal_load(&vb[sub + j * 32]);

        process(cur);

        #pragma unroll
        for (int j = 0; j < 4; ++j) cur[j] = nxt[j];
    }
    process(cur);  // it = 15 (peeled)

    // lanes 0 and 32 hold the two group partials
    acc += __shfl_xor(acc, 32, 64);

    __shared__ float sacc[4];
    if (l == 0) sacc[wave] = acc;
    __syncthreads();
    if (threadIdx.x == 0)
        partials[blk] = sacc[0] + sacc[1] + sacc[2] + sacc[3];
}

// Kernel 3: final loss mean. 1 block x 128 threads.
__global__ __launch_bounds__(128)
void k3_final(const float* __restrict__ simpos, const float* __restrict__ partials,
              float* __restrict__ out) {
    int bn = threadIdx.x;
    float ns = 0.f;
    for (int i = 0; i < NCHUNK; ++i)
        ns += partials[bn * NCHUNK + i];
    float sp = simpos[bn];
    float ep = expf(sp);
    float denom = fmaxf(ep + ns, 1e-7f);
    float loss = -logf(ep / denom);

    __shared__ float s[BN];
    s[bn] = loss;
    __syncthreads();
    #pragma unroll
    for (int st = 64; st > 0; st >>= 1) {
        if (bn < st) s[bn] += s[bn + st];
        __syncthreads();
    }
    if (bn == 0) out[0] = s[0] / (float)BN;
}

extern "C" void kernel_launch(void* const* d_in, const int* in_sizes, int n_in,
                              void* d_out, int out_size, void* d_ws, size_t ws_size,
                              hipStream_t stream) {
    const float* pred    = (const float*)d_in[0];  // (B, C, D)
    const float* pos     = (const float*)d_in[1];  // (B, N, D)
    const float* neg     = (const float*)d_in[2];  // (B, N, K, D)
    const float* centers = (const float*)d_in[3];  // (C, D)
    const int*   cats    = (const int*)d_in[4];    // (B, N)

    float* out = (float*)d_out;

    float* simpos   = (float*)d_ws;            // 128 floats
    float* partials = simpos + BN;             // 128*16 floats

    k2_neg<<<BN * NCHUNK, 256, 0, stream>>>(pred, pos, neg, centers, cats, simpos, partials);
    k3_final<<<1, 128, 0, stream>>>(simpos, partials, out);
}